// Round 7
// baseline (287.601 us; speedup 1.0000x reference)
//
#include <hip/hip_runtime.h>
#include <hip/hip_bf16.h>

// RWKV TimeMix forward, MI355X — single mega-kernel, contention-free flag
// barrier (r5 post-mortem: counter barrier's line ping-pong cost 160us/bar;
// this one has NO atomics-RMW: per-block flag stores + block-0 aggregation).
// Phases: P0 prep(mix + W bf16 cast) -> B1 -> P1 gemm3 (432 tiles) -> B2 ->
//         P2 scan (blocks 0..143) -> B3(144) -> P3 gemm_out (144 tiles).
// Blocks >=144 exit after arriving at B2. Co-residency: launch_bounds(256,2)
// => capacity 512 >= 432 (empirically confirmed by r5's completion).
// Barrier slots are fresh per launch (memsetAsync 24KB), replay-safe.

#define T_LEN 767
#define C_DIM 768
#define SZ (768 * 768)
#define R_CHUNK 4
#define QSZ (SZ / 4)
#define NBLK 432
#define NBLK_P3 144
#define SLOT_U32 2048          // 8 KB per barrier slot
#define GEN_OFF 1920           // gen word offset inside slot (> 431*4)

typedef __attribute__((ext_vector_type(4))) float f32x4;
typedef __attribute__((ext_vector_type(8))) short s16x8;
typedef __attribute__((ext_vector_type(4))) short s16x4;

__device__ __forceinline__ short bfbits(float f) {
    __hip_bfloat16 h = __float2bfloat16(f);
    return *reinterpret_cast<short*>(&h);
}

// Arrival: one release-store to own 16B-strided flag (no RMW anywhere).
__device__ __forceinline__ void bar_arrive(unsigned* slot) {
    __threadfence();                 // release this block's global writes
    __syncthreads();
    if (threadIdx.x == 0 && blockIdx.x != 0)
        __hip_atomic_store(slot + blockIdx.x * 4, 1u, __ATOMIC_RELEASE,
                           __HIP_MEMORY_SCOPE_AGENT);
}

// Wait: block 0 aggregates flags (256 threads in parallel), bumps gen;
// other blocks poll gen only (read-shared line).
__device__ __forceinline__ void bar_wait(unsigned* slot, int nblk) {
    if (blockIdx.x == 0) {
        for (int b = 1 + threadIdx.x; b < nblk; b += 256)
            while (__hip_atomic_load(slot + b * 4, __ATOMIC_ACQUIRE,
                                     __HIP_MEMORY_SCOPE_AGENT) == 0)
                __builtin_amdgcn_s_sleep(1);
        __syncthreads();
        __threadfence();             // order acquires before gen release
        if (threadIdx.x == 0)
            __hip_atomic_store(slot + GEN_OFF, 1u, __ATOMIC_RELEASE,
                               __HIP_MEMORY_SCOPE_AGENT);
    } else {
        if (threadIdx.x == 0)
            while (__hip_atomic_load(slot + GEN_OFF, __ATOMIC_ACQUIRE,
                                     __HIP_MEMORY_SCOPE_AGENT) == 0)
                __builtin_amdgcn_s_sleep(1);
    }
    __syncthreads();
    __threadfence();                 // acquire side for all lanes
}

// 64x64-tile GEMM: C = A(bf16) * B(bf16)^T, K=768, 1-deep register prefetch,
// padded LDS (r5-proven). epi: 0 plain, 1 exp(min(v,60)), 2 rows<767 only.
__device__ __forceinline__ void gemm_nt64(const __hip_bfloat16* __restrict__ A,
                                          const __hip_bfloat16* __restrict__ B,
                                          float* __restrict__ C,
                                          int bi, int bj, int epi)
{
    __shared__ __hip_bfloat16 lA[64][40];
    __shared__ __hip_bfloat16 lB[64][40];
    const int tid  = threadIdx.x;
    const int lane = tid & 63;
    const int wid  = tid >> 6;
    const int wr = wid >> 1, wc = wid & 1;  // 2x2 waves, 32x32 each
    const int srow = tid >> 2;              // staging row 0..63
    const int scol = (tid & 3) * 8;         // staging k-offset 0/8/16/24
    const int frow = lane & 15;             // MFMA A/B: row/col = lane&15
    const int kseg = (lane >> 4) * 8;       //           k = (lane>>4)*8 + j

    f32x4 acc[2][2] = {};

    const __hip_bfloat16* gA = A + (size_t)(bi * 64 + srow) * C_DIM + scol;
    const __hip_bfloat16* gB = B + (size_t)(bj * 64 + srow) * C_DIM + scol;

    s16x8 a0 = *(const s16x8*)gA;
    s16x8 b0 = *(const s16x8*)gB;
    for (int t = 0; t < 24; ++t) {
        s16x8 a1, b1;
        if (t < 23) {                       // prefetch next K-step; latency
            a1 = *(const s16x8*)(gA + (t + 1) * 32);   // hides under MFMA
            b1 = *(const s16x8*)(gB + (t + 1) * 32);
        }
        __syncthreads();
        *(s16x8*)&lA[srow][scol] = a0;
        *(s16x8*)&lB[srow][scol] = b0;
        __syncthreads();
        s16x8 af[2], bfr[2];
        #pragma unroll
        for (int m = 0; m < 2; ++m)
            af[m] = *(const s16x8*)&lA[wr * 32 + m * 16 + frow][kseg];
        #pragma unroll
        for (int n = 0; n < 2; ++n)
            bfr[n] = *(const s16x8*)&lB[wc * 32 + n * 16 + frow][kseg];
        #pragma unroll
        for (int m = 0; m < 2; ++m)
            #pragma unroll
            for (int n = 0; n < 2; ++n)
                acc[m][n] = __builtin_amdgcn_mfma_f32_16x16x32_bf16(
                    af[m], bfr[n], acc[m][n], 0, 0, 0);
        a0 = a1; b0 = b1;
    }

    // C/D layout: col = lane&15, row = (lane>>4)*4 + j   [m89-verified]
    int rbase = bi * 64 + wr * 32 + (lane >> 4) * 4;
    int cbase = bj * 64 + wc * 32 + (lane & 15);
    #pragma unroll
    for (int m = 0; m < 2; ++m) {
        #pragma unroll
        for (int n = 0; n < 2; ++n) {
            #pragma unroll
            for (int j = 0; j < 4; ++j) {
                int row = rbase + m * 16 + j;
                int col = cbase + n * 16;
                float v = acc[m][n][j];
                if (epi == 1) v = __expf(fminf(v, 60.f));
                if (epi != 2 || row < T_LEN)
                    C[(size_t)row * C_DIM + col] = v;
            }
        }
    }
}

__global__ __launch_bounds__(256, 2) void mega_kernel(
    const float* __restrict__ x, const float* __restrict__ td,
    const float* __restrict__ tf, const float* __restrict__ tmk,
    const float* __restrict__ tmv, const float* __restrict__ tmr,
    const float* __restrict__ Wk, const float* __restrict__ Wv,
    const float* __restrict__ Wr, const float* __restrict__ Wo,
    __hip_bfloat16* __restrict__ xkvr, __hip_bfloat16* __restrict__ Wb,
    float* __restrict__ kvr, __hip_bfloat16* __restrict__ rwkv,
    float* __restrict__ out, unsigned* __restrict__ bar)
{
    const int gt = blockIdx.x * 256 + threadIdx.x;
    const int nthr = NBLK * 256;

    // ---------------- P0: prep (mix + bf16 casts) ----------------
    for (int i = gt; i < 5 * QSZ; i += nthr) {
        int job  = i / QSZ;             // 0: mix, 1..4: Wk/Wv/Wr/Wo cast
        int base = (i - job * QSZ) * 4;
        if (job != 0) {
            const float* src = (job == 1) ? Wk : (job == 2) ? Wv
                             : (job == 3) ? Wr : Wo;
            f32x4 w = *(const f32x4*)(src + base);
            s16x4 o;
            #pragma unroll
            for (int j = 0; j < 4; ++j) o[j] = bfbits(w[j]);
            *(s16x4*)(Wb + (size_t)(job - 1) * SZ + base) = o;
            continue;
        }
        int t = base / C_DIM, c = base - t * C_DIM;
        if (t == T_LEN) {
            s16x4 z = {0, 0, 0, 0};
            *(s16x4*)(xkvr + base) = z;
            *(s16x4*)(xkvr + SZ + base) = z;
            *(s16x4*)(xkvr + 2 * SZ + base) = z;
            *(s16x4*)(rwkv + base) = z;       // pad row for P3 GEMM
            continue;
        }
        f32x4 xc = *(const f32x4*)(x + base);
        f32x4 xp = {0, 0, 0, 0};
        if (t) xp = *(const f32x4*)(x + base - C_DIM);
        f32x4 mk = *(const f32x4*)(tmk + c);
        f32x4 mv = *(const f32x4*)(tmv + c);
        f32x4 mr = *(const f32x4*)(tmr + c);
        s16x4 ok, ov, orr;
        #pragma unroll
        for (int j = 0; j < 4; ++j) {
            ok[j]  = bfbits(xc[j] * mk[j] + xp[j] * (1.f - mk[j]));
            ov[j]  = bfbits(xc[j] * mv[j] + xp[j] * (1.f - mv[j]));
            orr[j] = bfbits(xc[j] * mr[j] + xp[j] * (1.f - mr[j]));
        }
        *(s16x4*)(xkvr + base) = ok;
        *(s16x4*)(xkvr + SZ + base) = ov;
        *(s16x4*)(xkvr + 2 * SZ + base) = orr;
    }
    bar_arrive(bar);
    bar_wait(bar, NBLK);

    // ---------------- P1: k/v/r GEMMs (432 tiles, 1/block) ----------------
    {
        int z = blockIdx.x / 144, rem = blockIdx.x % 144;
        gemm_nt64(xkvr + (size_t)z * SZ, Wb + (size_t)z * SZ,
                  kvr + (size_t)z * SZ, rem / 12, rem % 12, z == 0 ? 1 : 0);
    }
    bar_arrive(bar + SLOT_U32);
    if (blockIdx.x >= NBLK_P3) return;      // done; blocks 0..143 carry on
    bar_wait(bar + SLOT_U32, NBLK);

    // ---------------- P2: windowed decay scan (blocks 0..143) ----------------
    // dm = exp(-exp(td)) <= ~0.11; dm^64 < 1e-45 -> 64-step warmup is exact.
    {
        const float* kb = kvr;
        const float* vb = kvr + SZ;
        const float* rb = kvr + 2 * SZ;
        int chunk = gt / 192;               // gt < 36864 here
        int d  = (gt - chunk * 192) * 4;
        int t0 = chunk * R_CHUNK;
        f32x4 dm, etf;
        {
            f32x4 tdv = *(const f32x4*)(td + d);
            f32x4 tfv = *(const f32x4*)(tf + d);
            #pragma unroll
            for (int j = 0; j < 4; ++j) {
                dm[j]  = __expf(-__expf(tdv[j]));
                etf[j] = __expf(tfv[j]);
            }
        }
        f32x4 a = {0, 0, 0, 0}, b = {0, 0, 0, 0};
        #pragma unroll 16
        for (int i = 64; i >= 1; --i) {
            int t = t0 - i;
            int tt = t < 0 ? 0 : t;
            f32x4 kk = *(const f32x4*)(kb + tt * C_DIM + d);
            f32x4 vv = *(const f32x4*)(vb + tt * C_DIM + d);
            if (t < 0) { f32x4 z = {0, 0, 0, 0}; kk = z; vv = z; }
            #pragma unroll
            for (int j = 0; j < 4; ++j) {
                a[j] = fmaf(dm[j], a[j], kk[j] * vv[j]);
                b[j] = fmaf(dm[j], b[j], kk[j]);
            }
        }
        int t1 = min(t0 + R_CHUNK, T_LEN);
        for (int t = t0; t < t1; ++t) {
            f32x4 kk = *(const f32x4*)(kb + t * C_DIM + d);
            f32x4 vv = *(const f32x4*)(vb + t * C_DIM + d);
            f32x4 rr = *(const f32x4*)(rb + t * C_DIM + d);
            s16x4 o;
            #pragma unroll
            for (int j = 0; j < 4; ++j) {
                float kv  = kk[j] * vv[j];
                float wkv = fmaf(etf[j], kv, a[j]);
                float wk  = fmaf(etf[j], kk[j], b[j]) + 1e-8f;
                float sig = 1.f / (1.f + __expf(-rr[j]));
                o[j] = bfbits(sig * wkv / wk);
                a[j] = fmaf(dm[j], a[j], kv);
                b[j] = fmaf(dm[j], b[j], kk[j]);
            }
            *(s16x4*)(rwkv + t * C_DIM + d) = o;
        }
    }
    bar_arrive(bar + 2 * SLOT_U32);
    bar_wait(bar + 2 * SLOT_U32, NBLK_P3);

    // ---------------- P3: output GEMM (144 tiles) ----------------
    gemm_nt64(rwkv, Wb + (size_t)3 * SZ, out,
              blockIdx.x / 12, blockIdx.x % 12, 2);
}

extern "C" void kernel_launch(void* const* d_in, const int* in_sizes, int n_in,
                              void* d_out, int out_size, void* d_ws, size_t ws_size,
                              hipStream_t stream)
{
    const float* x   = (const float*)d_in[0];
    const float* td  = (const float*)d_in[1];
    const float* tf  = (const float*)d_in[2];
    const float* tmk = (const float*)d_in[3];
    const float* tmv = (const float*)d_in[4];
    const float* tmr = (const float*)d_in[5];
    const float* Wk  = (const float*)d_in[6];
    const float* Wv  = (const float*)d_in[7];
    const float* Wr  = (const float*)d_in[8];
    const float* Wo  = (const float*)d_in[9];
    float* out = (float*)d_out;

    char* ws = (char*)d_ws;
    __hip_bfloat16* xkvr = (__hip_bfloat16*)ws;                        // 6*SZ B
    __hip_bfloat16* Wb   = (__hip_bfloat16*)(ws + (size_t)6 * SZ);     // 8*SZ B
    float*          kvr  = (float*)(ws + (size_t)14 * SZ);             // 12*SZ B
    __hip_bfloat16* rwkv = (__hip_bfloat16*)(ws + (size_t)26 * SZ);    // 2*SZ B
    unsigned*       bar  = (unsigned*)(ws + (size_t)28 * SZ);          // 24 KB

    hipMemsetAsync(bar, 0, 3 * SLOT_U32 * sizeof(unsigned), stream);
    mega_kernel<<<dim3(NBLK), dim3(256), 0, stream>>>(
        x, td, tf, tmk, tmv, tmr, Wk, Wv, Wr, Wo,
        xkvr, Wb, kvr, rwkv, out, bar);
}

// Round 8
// 54.419 us; speedup vs baseline: 5.2850x; 5.2850x over previous
//
#include <hip/hip_runtime.h>
#include <hip/hip_bf16.h>

// RWKV TimeMix forward, MI355X — 4 dispatches (round-2 anchor + safe deltas):
//   P0 prep: time-mix + bf16 cast + W f32->bf16 (vectorized, r3-proven)
//   P1 gemm3: k/v/r = xm @ W^T, 64x64 tiles, 1-deep register prefetch
//             (r5/r7-P1-proven inner loop), exp(min(.,60)) epilogue on k
//   P2 scan: windowed decay recurrence (64-step warmup exact in fp32)
//   P3 gemm_out: 32x32 tiles, 1 wave/block, grid 24x24=576 (all CUs busy)
// Lesson ledger: r3/r6 = don't put cvt/extra loads in the K-step; r5/r7 =
// software grid barriers cost ~100us/barrier on MI355X, never again.

#define T_LEN 767
#define C_DIM 768
#define SZ (768 * 768)
#define R_CHUNK 4

typedef __attribute__((ext_vector_type(4))) float f32x4;
typedef __attribute__((ext_vector_type(8))) short s16x8;
typedef __attribute__((ext_vector_type(4))) short s16x4;

__device__ __forceinline__ short bfbits(float f) {
    __hip_bfloat16 h = __float2bfloat16(f);
    return *reinterpret_cast<short*>(&h);
}

// P0: grid (576, 5), 256 thr. y==0: time-mix+cast (4 elems/thr). y 1..4: W cast.
__global__ __launch_bounds__(256) void prep_kernel(
    const float* __restrict__ x, const float* __restrict__ tmk,
    const float* __restrict__ tmv, const float* __restrict__ tmr,
    const float* __restrict__ Wk, const float* __restrict__ Wv,
    const float* __restrict__ Wr, const float* __restrict__ Wo,
    __hip_bfloat16* __restrict__ xkvr, __hip_bfloat16* __restrict__ Wb,
    __hip_bfloat16* __restrict__ rwkv)
{
    int base = (blockIdx.x * 256 + threadIdx.x) * 4;
    int job = blockIdx.y;
    if (job != 0) {
        const float* src = (job == 1) ? Wk : (job == 2) ? Wv : (job == 3) ? Wr : Wo;
        f32x4 w = *(const f32x4*)(src + base);
        s16x4 o;
        #pragma unroll
        for (int j = 0; j < 4; ++j) o[j] = bfbits(w[j]);
        *(s16x4*)(Wb + (size_t)(job - 1) * SZ + base) = o;
        return;
    }
    int t = base / C_DIM, c = base - t * C_DIM;
    if (t == T_LEN) {
        s16x4 z = {0, 0, 0, 0};
        *(s16x4*)(xkvr + base) = z;
        *(s16x4*)(xkvr + SZ + base) = z;
        *(s16x4*)(xkvr + 2 * SZ + base) = z;
        *(s16x4*)(rwkv + base) = z;   // pad row for P3 GEMM
        return;
    }
    f32x4 xc = *(const f32x4*)(x + base);
    f32x4 xp = {0, 0, 0, 0};
    if (t) xp = *(const f32x4*)(x + base - C_DIM);
    f32x4 mk = *(const f32x4*)(tmk + c);
    f32x4 mv = *(const f32x4*)(tmv + c);
    f32x4 mr = *(const f32x4*)(tmr + c);
    s16x4 ok, ov, orr;
    #pragma unroll
    for (int j = 0; j < 4; ++j) {
        ok[j]  = bfbits(xc[j] * mk[j] + xp[j] * (1.f - mk[j]));
        ov[j]  = bfbits(xc[j] * mv[j] + xp[j] * (1.f - mv[j]));
        orr[j] = bfbits(xc[j] * mr[j] + xp[j] * (1.f - mr[j]));
    }
    *(s16x4*)(xkvr + base) = ok;
    *(s16x4*)(xkvr + SZ + base) = ov;
    *(s16x4*)(xkvr + 2 * SZ + base) = orr;
}

// P1: 64x64-tile GEMM, C = A(bf16) @ B(bf16)^T, K=768, 1-deep reg prefetch.
// epi: 1 = exp(min(v,60)) on z==0, else plain. grid (12,12,3), 256 thr.
__global__ __launch_bounds__(256) void gemm3_kernel(
    const __hip_bfloat16* __restrict__ xkvr,
    const __hip_bfloat16* __restrict__ Wb, float* __restrict__ kvr)
{
    __shared__ __hip_bfloat16 lA[64][40];   // +8 pad (r2-proven)
    __shared__ __hip_bfloat16 lB[64][40];
    const int z = blockIdx.z;               // 0=k (exp epi), 1=v, 2=r
    const __hip_bfloat16* A = xkvr + (size_t)z * SZ;
    const __hip_bfloat16* B = Wb + (size_t)z * SZ;
    float* C = kvr + (size_t)z * SZ;
    const int bi = blockIdx.x, bj = blockIdx.y;
    const int tid  = threadIdx.x;
    const int lane = tid & 63;
    const int wid  = tid >> 6;
    const int wr = wid >> 1, wc = wid & 1;  // 2x2 waves, 32x32 each
    const int srow = tid >> 2;              // staging row 0..63
    const int scol = (tid & 3) * 8;         // staging k-offset 0/8/16/24
    const int frow = lane & 15;             // MFMA A/B: row/col = lane&15
    const int kseg = (lane >> 4) * 8;       //           k = (lane>>4)*8 + j

    f32x4 acc[2][2] = {};
    const __hip_bfloat16* gA = A + (size_t)(bi * 64 + srow) * C_DIM + scol;
    const __hip_bfloat16* gB = B + (size_t)(bj * 64 + srow) * C_DIM + scol;

    s16x8 a0 = *(const s16x8*)gA;
    s16x8 b0 = *(const s16x8*)gB;
    for (int t = 0; t < 24; ++t) {
        s16x8 a1, b1;
        if (t < 23) {                       // prefetch next K-step; its latency
            a1 = *(const s16x8*)(gA + (t + 1) * 32);  // hides under MFMA
            b1 = *(const s16x8*)(gB + (t + 1) * 32);
        }
        __syncthreads();
        *(s16x8*)&lA[srow][scol] = a0;
        *(s16x8*)&lB[srow][scol] = b0;
        __syncthreads();
        s16x8 af[2], bfr[2];
        #pragma unroll
        for (int m = 0; m < 2; ++m)
            af[m] = *(const s16x8*)&lA[wr * 32 + m * 16 + frow][kseg];
        #pragma unroll
        for (int n = 0; n < 2; ++n)
            bfr[n] = *(const s16x8*)&lB[wc * 32 + n * 16 + frow][kseg];
        #pragma unroll
        for (int m = 0; m < 2; ++m)
            #pragma unroll
            for (int n = 0; n < 2; ++n)
                acc[m][n] = __builtin_amdgcn_mfma_f32_16x16x32_bf16(
                    af[m], bfr[n], acc[m][n], 0, 0, 0);
        a0 = a1; b0 = b1;
    }

    // C/D layout: col = lane&15, row = (lane>>4)*4 + j   [m89-verified]
    int rbase = bi * 64 + wr * 32 + (lane >> 4) * 4;
    int cbase = bj * 64 + wc * 32 + (lane & 15);
    #pragma unroll
    for (int m = 0; m < 2; ++m)
        #pragma unroll
        for (int n = 0; n < 2; ++n)
            #pragma unroll
            for (int j = 0; j < 4; ++j) {
                float v = acc[m][n][j];
                if (z == 0) v = __expf(fminf(v, 60.f));
                C[(size_t)(rbase + m * 16 + j) * C_DIM + cbase + n * 16] = v;
            }
}

// P3: 32x32-tile GEMM, 1 wave/block, grid (24,24). out = rwkv @ Wo^T,
// rows<767 stored only (row 767 of rwkv is zeroed by prep).
__global__ __launch_bounds__(64) void gemm_out_kernel(
    const __hip_bfloat16* __restrict__ rwkv,
    const __hip_bfloat16* __restrict__ Wo_b, float* __restrict__ out)
{
    __shared__ __hip_bfloat16 lA[32][40];
    __shared__ __hip_bfloat16 lB[32][40];
    const int bi = blockIdx.x, bj = blockIdx.y;
    const int lane = threadIdx.x;           // 0..63
    const int srow = lane >> 1;             // staging row 0..31
    const int scol = (lane & 1) * 16;       // staging k-offset 0/16
    const int frow = lane & 15;
    const int kseg = (lane >> 4) * 8;

    f32x4 acc[2][2] = {};
    const __hip_bfloat16* gA = rwkv + (size_t)(bi * 32 + srow) * C_DIM + scol;
    const __hip_bfloat16* gB = Wo_b + (size_t)(bj * 32 + srow) * C_DIM + scol;

    s16x8 a0 = *(const s16x8*)gA,      a0h = *(const s16x8*)(gA + 8);
    s16x8 b0 = *(const s16x8*)gB,      b0h = *(const s16x8*)(gB + 8);
    for (int t = 0; t < 24; ++t) {
        s16x8 a1, a1h, b1, b1h;
        if (t < 23) {
            a1  = *(const s16x8*)(gA + (t + 1) * 32);
            a1h = *(const s16x8*)(gA + (t + 1) * 32 + 8);
            b1  = *(const s16x8*)(gB + (t + 1) * 32);
            b1h = *(const s16x8*)(gB + (t + 1) * 32 + 8);
        }
        __syncthreads();
        *(s16x8*)&lA[srow][scol]     = a0;
        *(s16x8*)&lA[srow][scol + 8] = a0h;
        *(s16x8*)&lB[srow][scol]     = b0;
        *(s16x8*)&lB[srow][scol + 8] = b0h;
        __syncthreads();
        s16x8 af[2], bfr[2];
        #pragma unroll
        for (int m = 0; m < 2; ++m)
            af[m] = *(const s16x8*)&lA[m * 16 + frow][kseg];
        #pragma unroll
        for (int n = 0; n < 2; ++n)
            bfr[n] = *(const s16x8*)&lB[n * 16 + frow][kseg];
        #pragma unroll
        for (int m = 0; m < 2; ++m)
            #pragma unroll
            for (int n = 0; n < 2; ++n)
                acc[m][n] = __builtin_amdgcn_mfma_f32_16x16x32_bf16(
                    af[m], bfr[n], acc[m][n], 0, 0, 0);
        a0 = a1; a0h = a1h; b0 = b1; b0h = b1h;
    }

    int rbase = bi * 32 + (lane >> 4) * 4;
    int cbase = bj * 32 + (lane & 15);
    #pragma unroll
    for (int m = 0; m < 2; ++m)
        #pragma unroll
        for (int n = 0; n < 2; ++n)
            #pragma unroll
            for (int j = 0; j < 4; ++j) {
                int row = rbase + m * 16 + j;
                if (row < T_LEN)
                    out[(size_t)row * C_DIM + cbase + n * 16] = acc[m][n][j];
            }
}

// P2: windowed decay scan, 4 channels/thread. dm = exp(-exp(td)) <= ~0.11;
// dm^64 < 1e-45 -> 64-step warmup from zero state is exact in fp32.
// grid (3, 192), 64 threads.
__global__ __launch_bounds__(64) void scan_kernel(
    const float* __restrict__ kb, const float* __restrict__ vb,
    const float* __restrict__ rb, const float* __restrict__ td,
    const float* __restrict__ tf, __hip_bfloat16* __restrict__ rwkv)
{
    int d  = (blockIdx.x * 64 + threadIdx.x) * 4;
    int t0 = blockIdx.y * R_CHUNK;
    f32x4 dm, etf;
    {
        f32x4 tdv = *(const f32x4*)(td + d);
        f32x4 tfv = *(const f32x4*)(tf + d);
        #pragma unroll
        for (int j = 0; j < 4; ++j) {
            dm[j]  = __expf(-__expf(tdv[j]));
            etf[j] = __expf(tfv[j]);
        }
    }
    f32x4 a = {0, 0, 0, 0}, b = {0, 0, 0, 0};
    #pragma unroll 16
    for (int i = 64; i >= 1; --i) {
        int t = t0 - i;
        int tt = t < 0 ? 0 : t;
        f32x4 kk = *(const f32x4*)(kb + tt * C_DIM + d);
        f32x4 vv = *(const f32x4*)(vb + tt * C_DIM + d);
        if (t < 0) { f32x4 z = {0, 0, 0, 0}; kk = z; vv = z; }
        #pragma unroll
        for (int j = 0; j < 4; ++j) {
            a[j] = fmaf(dm[j], a[j], kk[j] * vv[j]);
            b[j] = fmaf(dm[j], b[j], kk[j]);
        }
    }
    int t1 = min(t0 + R_CHUNK, T_LEN);
    for (int t = t0; t < t1; ++t) {
        f32x4 kk = *(const f32x4*)(kb + t * C_DIM + d);
        f32x4 vv = *(const f32x4*)(vb + t * C_DIM + d);
        f32x4 rr = *(const f32x4*)(rb + t * C_DIM + d);
        s16x4 o;
        #pragma unroll
        for (int j = 0; j < 4; ++j) {
            float kv  = kk[j] * vv[j];
            float wkv = fmaf(etf[j], kv, a[j]);
            float wk  = fmaf(etf[j], kk[j], b[j]) + 1e-8f;
            float sig = 1.f / (1.f + __expf(-rr[j]));
            o[j] = bfbits(sig * wkv / wk);
            a[j] = fmaf(dm[j], a[j], kv);
            b[j] = fmaf(dm[j], b[j], kk[j]);
        }
        *(s16x4*)(rwkv + t * C_DIM + d) = o;
    }
}

extern "C" void kernel_launch(void* const* d_in, const int* in_sizes, int n_in,
                              void* d_out, int out_size, void* d_ws, size_t ws_size,
                              hipStream_t stream)
{
    const float* x   = (const float*)d_in[0];
    const float* td  = (const float*)d_in[1];
    const float* tf  = (const float*)d_in[2];
    const float* tmk = (const float*)d_in[3];
    const float* tmv = (const float*)d_in[4];
    const float* tmr = (const float*)d_in[5];
    const float* Wk  = (const float*)d_in[6];
    const float* Wv  = (const float*)d_in[7];
    const float* Wr  = (const float*)d_in[8];
    const float* Wo  = (const float*)d_in[9];
    float* out = (float*)d_out;

    char* ws = (char*)d_ws;
    __hip_bfloat16* xkvr = (__hip_bfloat16*)ws;                        // 6*SZ B
    __hip_bfloat16* Wb   = (__hip_bfloat16*)(ws + (size_t)6 * SZ);     // 8*SZ B
    float*          kvr  = (float*)(ws + (size_t)14 * SZ);             // 12*SZ B
    __hip_bfloat16* rwkv = (__hip_bfloat16*)(ws + (size_t)26 * SZ);    // 2*SZ B

    prep_kernel<<<dim3(SZ / 1024, 5), 256, 0, stream>>>(
        x, tmk, tmv, tmr, Wk, Wv, Wr, Wo, xkvr, Wb, rwkv);
    gemm3_kernel<<<dim3(12, 12, 3), 256, 0, stream>>>(xkvr, Wb, kvr);
    scan_kernel<<<dim3(3, 192), 64, 0, stream>>>(
        kvr, kvr + SZ, kvr + 2 * SZ, td, tf, rwkv);
    gemm_out_kernel<<<dim3(24, 24), 64, 0, stream>>>(rwkv, Wb + (size_t)3 * SZ, out);
}

// Round 9
// 41.159 us; speedup vs baseline: 6.9875x; 1.3221x over previous
//
#include <hip/hip_runtime.h>
#include <hip/hip_bf16.h>

// RWKV TimeMix forward, MI355X — EXACT round-2 structure (44.5us anchor) with
// ONE change: 1-deep register prefetch in gemm_nt64 (both GEMM dispatches).
// Ledger: r3(+6)/r6(+22)/r8(+10) all multi-change regressions vs r2;
// r5/r7: software grid barriers cost ~100us/barrier on MI355X — never again.
// ws layout (SZ = 768*768):
//   [0)          xkvr  bf16 3*SZ  (xk,xv,xr; row 767 zeroed)
//   [3*SZ*2)     Wb    bf16 4*SZ  (Wk,Wv,Wr,Wo)
//   [7*SZ*2)     kvr   f32  3*SZ  (k=exp(min(.,60)), v, r)  [T-major]
//   [7*SZ*2+3*SZ*4) rwkv bf16 SZ  (row 767 zeroed)

#define T_LEN 767
#define C_DIM 768
#define SZ (768 * 768)
#define R_CHUNK 4   // outputs per scan thread; window = 64 warmup steps

typedef __attribute__((ext_vector_type(4))) float f32x4;
typedef __attribute__((ext_vector_type(8))) short s16x8;

// Fused prep: grid (2304, 5). y==0: time-mix + bf16 cast (3 outputs/elem).
// y in 1..4: Wk/Wv/Wr/Wo f32->bf16.   [verbatim round-2]
__global__ __launch_bounds__(256) void prep_kernel(
    const float* __restrict__ x, const float* __restrict__ tmk,
    const float* __restrict__ tmv, const float* __restrict__ tmr,
    const float* __restrict__ Wk, const float* __restrict__ Wv,
    const float* __restrict__ Wr, const float* __restrict__ Wo,
    __hip_bfloat16* __restrict__ xkvr, __hip_bfloat16* __restrict__ Wb,
    __hip_bfloat16* __restrict__ rwkv)
{
    int idx = blockIdx.x * 256 + threadIdx.x;   // 0 .. SZ-1
    int job = blockIdx.y;
    if (job != 0) {
        const float* src = (job == 1) ? Wk : (job == 2) ? Wv : (job == 3) ? Wr : Wo;
        Wb[(size_t)(job - 1) * SZ + idx] = __float2bfloat16(src[idx]);
        return;
    }
    int t = idx / C_DIM;
    int c = idx - t * C_DIM;
    if (t == T_LEN) {
        __hip_bfloat16 z = __float2bfloat16(0.f);
        xkvr[idx] = z; xkvr[SZ + idx] = z; xkvr[2 * SZ + idx] = z;
        rwkv[idx] = z;   // padded row for final GEMM
        return;
    }
    float xc = x[idx];
    float xp = (t == 0) ? 0.f : x[idx - C_DIM];
    float mk = tmk[c], mv = tmv[c], mr = tmr[c];
    xkvr[idx]          = __float2bfloat16(xc * mk + xp * (1.f - mk));
    xkvr[SZ + idx]     = __float2bfloat16(xc * mv + xp * (1.f - mv));
    xkvr[2 * SZ + idx] = __float2bfloat16(xc * mr + xp * (1.f - mr));
}

// 64x64-tile GEMM: C[bi*64.., bj*64..] = A * B^T (row-major, K=768).
// Round-2 body + ONE change: 1-deep register prefetch of the next K-step.
// epi: 0 = plain store, 1 = exp(min(v,60)), 2 = store only rows < 767
__device__ __forceinline__ void gemm_nt64(const __hip_bfloat16* __restrict__ A,
                                          const __hip_bfloat16* __restrict__ B,
                                          float* __restrict__ C,
                                          int bi, int bj, int epi)
{
    __shared__ __hip_bfloat16 lA[64][40];  // +8 pad: breaks bank conflicts
    __shared__ __hip_bfloat16 lB[64][40];
    const int tid  = threadIdx.x;
    const int lane = tid & 63;
    const int wid  = tid >> 6;
    const int wr = wid >> 1, wc = wid & 1;  // 2x2 waves, 32x32 each
    const int srow = tid >> 2;              // staging row 0..63
    const int scol = (tid & 3) * 8;         // staging k-offset 0/8/16/24
    const int frow = lane & 15;             // MFMA A/B: row/col = lane&15
    const int kseg = (lane >> 4) * 8;       //           k = (lane>>4)*8 + j

    f32x4 acc[2][2] = {};

    const __hip_bfloat16* gA = A + (size_t)(bi * 64 + srow) * C_DIM + scol;
    const __hip_bfloat16* gB = B + (size_t)(bj * 64 + srow) * C_DIM + scol;

    s16x8 a0 = *(const s16x8*)gA;
    s16x8 b0 = *(const s16x8*)gB;
    for (int t = 0; t < 24; ++t) {
        s16x8 a1, b1;
        if (t < 23) {                       // prefetch next K-step: its L2
            a1 = *(const s16x8*)(gA + (t + 1) * 32);  // latency hides under
            b1 = *(const s16x8*)(gB + (t + 1) * 32);  // this step's MFMA
        }
        __syncthreads();
        *(s16x8*)&lA[srow][scol] = a0;
        *(s16x8*)&lB[srow][scol] = b0;
        __syncthreads();
        s16x8 af[2], bfr[2];
        #pragma unroll
        for (int m = 0; m < 2; ++m)
            af[m] = *(const s16x8*)&lA[wr * 32 + m * 16 + frow][kseg];
        #pragma unroll
        for (int n = 0; n < 2; ++n)
            bfr[n] = *(const s16x8*)&lB[wc * 32 + n * 16 + frow][kseg];
        #pragma unroll
        for (int m = 0; m < 2; ++m)
            #pragma unroll
            for (int n = 0; n < 2; ++n)
                acc[m][n] = __builtin_amdgcn_mfma_f32_16x16x32_bf16(
                    af[m], bfr[n], acc[m][n], 0, 0, 0);
        a0 = a1; b0 = b1;
    }

    // C/D layout: col = lane&15, row = (lane>>4)*4 + j   [m89-verified]
    int rbase = bi * 64 + wr * 32 + (lane >> 4) * 4;
    int cbase = bj * 64 + wc * 32 + (lane & 15);
    #pragma unroll
    for (int m = 0; m < 2; ++m) {
        #pragma unroll
        for (int n = 0; n < 2; ++n) {
            #pragma unroll
            for (int j = 0; j < 4; ++j) {
                int row = rbase + m * 16 + j;
                int col = cbase + n * 16;
                float v = acc[m][n][j];
                if (epi == 1) v = __expf(fminf(v, 60.f));
                if (epi != 2 || row < T_LEN)
                    C[(size_t)row * C_DIM + col] = v;
            }
        }
    }
}

__global__ __launch_bounds__(256) void gemm3_kernel(
    const __hip_bfloat16* __restrict__ xkvr,
    const __hip_bfloat16* __restrict__ Wb, float* __restrict__ kvr)
{
    int z = blockIdx.z;  // 0=k (exp epilogue), 1=v, 2=r
    gemm_nt64(xkvr + (size_t)z * SZ, Wb + (size_t)z * SZ, kvr + (size_t)z * SZ,
              blockIdx.x, blockIdx.y, z == 0 ? 1 : 0);
}

__global__ __launch_bounds__(256) void gemm_out_kernel(
    const __hip_bfloat16* __restrict__ rwkv,
    const __hip_bfloat16* __restrict__ Wo_b, float* __restrict__ out)
{
    gemm_nt64(rwkv, Wo_b, out, blockIdx.x, blockIdx.y, 2);
}

// Windowed decay scan [verbatim round-2]. dm = exp(-exp(td)) <= ~0.11, so
// dm^64 < 1e-45 == 0.0f in fp32: fixed 64-step warmup from zero is EXACT.
// Each thread emits R_CHUNK consecutive outputs. grid (3, 192), 256 thr.
__global__ __launch_bounds__(256) void scan_kernel(
    const float* __restrict__ kb, const float* __restrict__ vb,
    const float* __restrict__ rb, const float* __restrict__ td,
    const float* __restrict__ tf, __hip_bfloat16* __restrict__ rwkv)
{
    int d  = blockIdx.x * 256 + threadIdx.x;  // grid.x = 3
    int t0 = blockIdx.y * R_CHUNK;
    float dm  = __expf(-__expf(td[d]));
    float etf = __expf(tf[d]);
    float a = 0.f, b = 0.f;
    // fixed-length warmup: t = t0-64 .. t0-1 (clamped loads, zeroed weights)
    #pragma unroll 16
    for (int i = 64; i >= 1; --i) {
        int t  = t0 - i;
        int tt = t < 0 ? 0 : t;
        float kk = kb[tt * C_DIM + d];
        float vv = vb[tt * C_DIM + d];
        if (t < 0) { kk = 0.f; vv = 0.f; }
        a = fmaf(dm, a, kk * vv);
        b = fmaf(dm, b, kk);
    }
    int t1 = min(t0 + R_CHUNK, T_LEN);
    #pragma unroll
    for (int t = t0; t < t1; ++t) {
        float kk = kb[t * C_DIM + d];
        float vv = vb[t * C_DIM + d];
        float kv = kk * vv;
        float wkv = fmaf(etf, kv, a);
        float wk  = fmaf(etf, kk, b) + 1e-8f;
        float rr  = rb[t * C_DIM + d];
        float sig = 1.f / (1.f + __expf(-rr));
        rwkv[t * C_DIM + d] = __float2bfloat16(sig * wkv / wk);
        a = fmaf(dm, a, kv);
        b = fmaf(dm, b, kk);
    }
}

extern "C" void kernel_launch(void* const* d_in, const int* in_sizes, int n_in,
                              void* d_out, int out_size, void* d_ws, size_t ws_size,
                              hipStream_t stream)
{
    const float* x   = (const float*)d_in[0];
    const float* td  = (const float*)d_in[1];
    const float* tf  = (const float*)d_in[2];
    const float* tmk = (const float*)d_in[3];
    const float* tmv = (const float*)d_in[4];
    const float* tmr = (const float*)d_in[5];
    const float* Wk  = (const float*)d_in[6];
    const float* Wv  = (const float*)d_in[7];
    const float* Wr  = (const float*)d_in[8];
    const float* Wo  = (const float*)d_in[9];
    float* out = (float*)d_out;

    char* ws = (char*)d_ws;
    __hip_bfloat16* xkvr = (__hip_bfloat16*)ws;
    __hip_bfloat16* Wb   = (__hip_bfloat16*)(ws + (size_t)3 * SZ * 2);
    float*          kvr  = (float*)(ws + (size_t)7 * SZ * 2);
    __hip_bfloat16* rwkv = (__hip_bfloat16*)(ws + (size_t)7 * SZ * 2 + (size_t)3 * SZ * 4);

    prep_kernel<<<dim3(SZ / 256, 5), 256, 0, stream>>>(
        x, tmk, tmv, tmr, Wk, Wv, Wr, Wo, xkvr, Wb, rwkv);
    gemm3_kernel<<<dim3(12, 12, 3), 256, 0, stream>>>(xkvr, Wb, kvr);
    scan_kernel<<<dim3(3, (T_LEN + R_CHUNK - 1) / R_CHUNK), 256, 0, stream>>>(
        kvr, kvr + SZ, kvr + 2 * SZ, td, tf, rwkv);
    gemm_out_kernel<<<dim3(12, 12), 256, 0, stream>>>(rwkv, Wb + (size_t)3 * SZ, out);
}

// Round 10
// 38.897 us; speedup vs baseline: 7.3938x; 1.0582x over previous
//
#include <hip/hip_runtime.h>
#include <hip/hip_bf16.h>

// RWKV TimeMix forward, MI355X — r9 anchor (41.2us) with ONE change:
// gemm_nt64 K_STEP 32 -> 64 (12 iters, half the barriers, 8 MFMA/step).
// Ledger: r2=44.5; r9=+prefetch=41.2 (confirmed); r3/r6/r8 multi-change
// regressions; r5/r7 software grid barriers ~100us/barrier — never again.
// ws layout (SZ = 768*768):
//   [0)          xkvr  bf16 3*SZ  (xk,xv,xr; row 767 zeroed)
//   [3*SZ*2)     Wb    bf16 4*SZ  (Wk,Wv,Wr,Wo)
//   [7*SZ*2)     kvr   f32  3*SZ  (k=exp(min(.,60)), v, r)  [T-major]
//   [7*SZ*2+3*SZ*4) rwkv bf16 SZ  (row 767 zeroed)

#define T_LEN 767
#define C_DIM 768
#define SZ (768 * 768)
#define R_CHUNK 4   // outputs per scan thread; window = 64 warmup steps

typedef __attribute__((ext_vector_type(4))) float f32x4;
typedef __attribute__((ext_vector_type(8))) short s16x8;

// Fused prep: grid (2304, 5). y==0: time-mix + bf16 cast (3 outputs/elem).
// y in 1..4: Wk/Wv/Wr/Wo f32->bf16.   [verbatim r2/r9]
__global__ __launch_bounds__(256) void prep_kernel(
    const float* __restrict__ x, const float* __restrict__ tmk,
    const float* __restrict__ tmv, const float* __restrict__ tmr,
    const float* __restrict__ Wk, const float* __restrict__ Wv,
    const float* __restrict__ Wr, const float* __restrict__ Wo,
    __hip_bfloat16* __restrict__ xkvr, __hip_bfloat16* __restrict__ Wb,
    __hip_bfloat16* __restrict__ rwkv)
{
    int idx = blockIdx.x * 256 + threadIdx.x;   // 0 .. SZ-1
    int job = blockIdx.y;
    if (job != 0) {
        const float* src = (job == 1) ? Wk : (job == 2) ? Wv : (job == 3) ? Wr : Wo;
        Wb[(size_t)(job - 1) * SZ + idx] = __float2bfloat16(src[idx]);
        return;
    }
    int t = idx / C_DIM;
    int c = idx - t * C_DIM;
    if (t == T_LEN) {
        __hip_bfloat16 z = __float2bfloat16(0.f);
        xkvr[idx] = z; xkvr[SZ + idx] = z; xkvr[2 * SZ + idx] = z;
        rwkv[idx] = z;   // padded row for final GEMM
        return;
    }
    float xc = x[idx];
    float xp = (t == 0) ? 0.f : x[idx - C_DIM];
    float mk = tmk[c], mv = tmv[c], mr = tmr[c];
    xkvr[idx]          = __float2bfloat16(xc * mk + xp * (1.f - mk));
    xkvr[SZ + idx]     = __float2bfloat16(xc * mv + xp * (1.f - mv));
    xkvr[2 * SZ + idx] = __float2bfloat16(xc * mr + xp * (1.f - mr));
}

// 64x64-tile GEMM: C[bi*64.., bj*64..] = A * B^T (row-major, K=768).
// K_STEP=64: 12 iters, 1-deep register prefetch, 8 MFMA/iter.
// epi: 0 = plain store, 1 = exp(min(v,60)), 2 = store only rows < 767
__device__ __forceinline__ void gemm_nt64(const __hip_bfloat16* __restrict__ A,
                                          const __hip_bfloat16* __restrict__ B,
                                          float* __restrict__ C,
                                          int bi, int bj, int epi)
{
    __shared__ __hip_bfloat16 lA[64][72];  // +8 pad: 2-way banks only (free)
    __shared__ __hip_bfloat16 lB[64][72];
    const int tid  = threadIdx.x;
    const int lane = tid & 63;
    const int wid  = tid >> 6;
    const int wr = wid >> 1, wc = wid & 1;  // 2x2 waves, 32x32 each
    const int srow = tid >> 2;              // staging row 0..63
    const int scol = (tid & 3) * 16;        // staging k-offset 0/16/32/48
    const int frow = lane & 15;             // MFMA A/B: row/col = lane&15
    const int kseg = (lane >> 4) * 8;       //           k = (lane>>4)*8 + j

    f32x4 acc[2][2] = {};

    const __hip_bfloat16* gA = A + (size_t)(bi * 64 + srow) * C_DIM + scol;
    const __hip_bfloat16* gB = B + (size_t)(bj * 64 + srow) * C_DIM + scol;

    s16x8 a0l = *(const s16x8*)gA,       a0h = *(const s16x8*)(gA + 8);
    s16x8 b0l = *(const s16x8*)gB,       b0h = *(const s16x8*)(gB + 8);
    for (int t = 0; t < 12; ++t) {
        s16x8 a1l, a1h, b1l, b1h;
        if (t < 11) {                       // prefetch next K-step: its L2
            const __hip_bfloat16* pA = gA + (t + 1) * 64;   // latency hides
            const __hip_bfloat16* pB = gB + (t + 1) * 64;   // under this
            a1l = *(const s16x8*)pA;  a1h = *(const s16x8*)(pA + 8);  // step's
            b1l = *(const s16x8*)pB;  b1h = *(const s16x8*)(pB + 8);  // MFMAs
        }
        __syncthreads();
        *(s16x8*)&lA[srow][scol]     = a0l;
        *(s16x8*)&lA[srow][scol + 8] = a0h;
        *(s16x8*)&lB[srow][scol]     = b0l;
        *(s16x8*)&lB[srow][scol + 8] = b0h;
        __syncthreads();
        s16x8 af[2][2], bfr[2][2];          // [ksub][m/n]
        #pragma unroll
        for (int ks = 0; ks < 2; ++ks) {
            #pragma unroll
            for (int m = 0; m < 2; ++m) {
                af[ks][m]  = *(const s16x8*)&lA[wr * 32 + m * 16 + frow][ks * 32 + kseg];
                bfr[ks][m] = *(const s16x8*)&lB[wc * 32 + m * 16 + frow][ks * 32 + kseg];
            }
        }
        #pragma unroll
        for (int ks = 0; ks < 2; ++ks)
            #pragma unroll
            for (int m = 0; m < 2; ++m)
                #pragma unroll
                for (int n = 0; n < 2; ++n)
                    acc[m][n] = __builtin_amdgcn_mfma_f32_16x16x32_bf16(
                        af[ks][m], bfr[ks][n], acc[m][n], 0, 0, 0);
        a0l = a1l; a0h = a1h; b0l = b1l; b0h = b1h;
    }

    // C/D layout: col = lane&15, row = (lane>>4)*4 + j   [m89-verified]
    int rbase = bi * 64 + wr * 32 + (lane >> 4) * 4;
    int cbase = bj * 64 + wc * 32 + (lane & 15);
    #pragma unroll
    for (int m = 0; m < 2; ++m) {
        #pragma unroll
        for (int n = 0; n < 2; ++n) {
            #pragma unroll
            for (int j = 0; j < 4; ++j) {
                int row = rbase + m * 16 + j;
                int col = cbase + n * 16;
                float v = acc[m][n][j];
                if (epi == 1) v = __expf(fminf(v, 60.f));
                if (epi != 2 || row < T_LEN)
                    C[(size_t)row * C_DIM + col] = v;
            }
        }
    }
}

__global__ __launch_bounds__(256) void gemm3_kernel(
    const __hip_bfloat16* __restrict__ xkvr,
    const __hip_bfloat16* __restrict__ Wb, float* __restrict__ kvr)
{
    int z = blockIdx.z;  // 0=k (exp epilogue), 1=v, 2=r
    gemm_nt64(xkvr + (size_t)z * SZ, Wb + (size_t)z * SZ, kvr + (size_t)z * SZ,
              blockIdx.x, blockIdx.y, z == 0 ? 1 : 0);
}

__global__ __launch_bounds__(256) void gemm_out_kernel(
    const __hip_bfloat16* __restrict__ rwkv,
    const __hip_bfloat16* __restrict__ Wo_b, float* __restrict__ out)
{
    gemm_nt64(rwkv, Wo_b, out, blockIdx.x, blockIdx.y, 2);
}

// Windowed decay scan [verbatim r2/r9]. dm = exp(-exp(td)) <= ~0.11, so
// dm^64 < 1e-45 == 0.0f in fp32: fixed 64-step warmup from zero is EXACT.
// Each thread emits R_CHUNK consecutive outputs. grid (3, 192), 256 thr.
__global__ __launch_bounds__(256) void scan_kernel(
    const float* __restrict__ kb, const float* __restrict__ vb,
    const float* __restrict__ rb, const float* __restrict__ td,
    const float* __restrict__ tf, __hip_bfloat16* __restrict__ rwkv)
{
    int d  = blockIdx.x * 256 + threadIdx.x;  // grid.x = 3
    int t0 = blockIdx.y * R_CHUNK;
    float dm  = __expf(-__expf(td[d]));
    float etf = __expf(tf[d]);
    float a = 0.f, b = 0.f;
    // fixed-length warmup: t = t0-64 .. t0-1 (clamped loads, zeroed weights)
    #pragma unroll 16
    for (int i = 64; i >= 1; --i) {
        int t  = t0 - i;
        int tt = t < 0 ? 0 : t;
        float kk = kb[tt * C_DIM + d];
        float vv = vb[tt * C_DIM + d];
        if (t < 0) { kk = 0.f; vv = 0.f; }
        a = fmaf(dm, a, kk * vv);
        b = fmaf(dm, b, kk);
    }
    int t1 = min(t0 + R_CHUNK, T_LEN);
    #pragma unroll
    for (int t = t0; t < t1; ++t) {
        float kk = kb[t * C_DIM + d];
        float vv = vb[t * C_DIM + d];
        float kv = kk * vv;
        float wkv = fmaf(etf, kv, a);
        float wk  = fmaf(etf, kk, b) + 1e-8f;
        float rr  = rb[t * C_DIM + d];
        float sig = 1.f / (1.f + __expf(-rr));
        rwkv[t * C_DIM + d] = __float2bfloat16(sig * wkv / wk);
        a = fmaf(dm, a, kv);
        b = fmaf(dm, b, kk);
    }
}

extern "C" void kernel_launch(void* const* d_in, const int* in_sizes, int n_in,
                              void* d_out, int out_size, void* d_ws, size_t ws_size,
                              hipStream_t stream)
{
    const float* x   = (const float*)d_in[0];
    const float* td  = (const float*)d_in[1];
    const float* tf  = (const float*)d_in[2];
    const float* tmk = (const float*)d_in[3];
    const float* tmv = (const float*)d_in[4];
    const float* tmr = (const float*)d_in[5];
    const float* Wk  = (const float*)d_in[6];
    const float* Wv  = (const float*)d_in[7];
    const float* Wr  = (const float*)d_in[8];
    const float* Wo  = (const float*)d_in[9];
    float* out = (float*)d_out;

    char* ws = (char*)d_ws;
    __hip_bfloat16* xkvr = (__hip_bfloat16*)ws;
    __hip_bfloat16* Wb   = (__hip_bfloat16*)(ws + (size_t)3 * SZ * 2);
    float*          kvr  = (float*)(ws + (size_t)7 * SZ * 2);
    __hip_bfloat16* rwkv = (__hip_bfloat16*)(ws + (size_t)7 * SZ * 2 + (size_t)3 * SZ * 4);

    prep_kernel<<<dim3(SZ / 256, 5), 256, 0, stream>>>(
        x, tmk, tmv, tmr, Wk, Wv, Wr, Wo, xkvr, Wb, rwkv);
    gemm3_kernel<<<dim3(12, 12, 3), 256, 0, stream>>>(xkvr, Wb, kvr);
    scan_kernel<<<dim3(3, (T_LEN + R_CHUNK - 1) / R_CHUNK), 256, 0, stream>>>(
        kvr, kvr + SZ, kvr + 2 * SZ, td, tf, rwkv);
    gemm_out_kernel<<<dim3(12, 12), 256, 0, stream>>>(rwkv, Wb + (size_t)3 * SZ, out);
}

// Round 11
// 36.789 us; speedup vs baseline: 7.8175x; 1.0573x over previous
//
#include <hip/hip_runtime.h>
#include <hip/hip_bf16.h>

// RWKV TimeMix forward, MI355X — r10 anchor (38.9us) with ONE change:
// scan warmup 64 -> 32 steps (weight at lag 33 is exp(-33*e^td) <= ~2e-26:
// dropping it is ~1e-23 absolute, 21 orders below the 3.3e-2 threshold).
// Ledger: r2=44.5; r9 +prefetch=41.2; r10 +K_STEP64=38.9 (both confirmed);
// r3/r6/r8 multi-change regressions; r5/r7 sw grid barriers ~100us/barrier.
// ws layout (SZ = 768*768):
//   [0)          xkvr  bf16 3*SZ  (xk,xv,xr; row 767 zeroed)
//   [3*SZ*2)     Wb    bf16 4*SZ  (Wk,Wv,Wr,Wo)
//   [7*SZ*2)     kvr   f32  3*SZ  (k=exp(min(.,60)), v, r)  [T-major]
//   [7*SZ*2+3*SZ*4) rwkv bf16 SZ  (row 767 zeroed)

#define T_LEN 767
#define C_DIM 768
#define SZ (768 * 768)
#define R_CHUNK 4    // outputs per scan thread
#define WARMUP 32    // decay window; exp(-33*e^0.6)*|kv| ~ 1e-23 << tol

typedef __attribute__((ext_vector_type(4))) float f32x4;
typedef __attribute__((ext_vector_type(8))) short s16x8;

// Fused prep: grid (2304, 5). y==0: time-mix + bf16 cast (3 outputs/elem).
// y in 1..4: Wk/Wv/Wr/Wo f32->bf16.   [verbatim r2/r9/r10]
__global__ __launch_bounds__(256) void prep_kernel(
    const float* __restrict__ x, const float* __restrict__ tmk,
    const float* __restrict__ tmv, const float* __restrict__ tmr,
    const float* __restrict__ Wk, const float* __restrict__ Wv,
    const float* __restrict__ Wr, const float* __restrict__ Wo,
    __hip_bfloat16* __restrict__ xkvr, __hip_bfloat16* __restrict__ Wb,
    __hip_bfloat16* __restrict__ rwkv)
{
    int idx = blockIdx.x * 256 + threadIdx.x;   // 0 .. SZ-1
    int job = blockIdx.y;
    if (job != 0) {
        const float* src = (job == 1) ? Wk : (job == 2) ? Wv : (job == 3) ? Wr : Wo;
        Wb[(size_t)(job - 1) * SZ + idx] = __float2bfloat16(src[idx]);
        return;
    }
    int t = idx / C_DIM;
    int c = idx - t * C_DIM;
    if (t == T_LEN) {
        __hip_bfloat16 z = __float2bfloat16(0.f);
        xkvr[idx] = z; xkvr[SZ + idx] = z; xkvr[2 * SZ + idx] = z;
        rwkv[idx] = z;   // padded row for final GEMM
        return;
    }
    float xc = x[idx];
    float xp = (t == 0) ? 0.f : x[idx - C_DIM];
    float mk = tmk[c], mv = tmv[c], mr = tmr[c];
    xkvr[idx]          = __float2bfloat16(xc * mk + xp * (1.f - mk));
    xkvr[SZ + idx]     = __float2bfloat16(xc * mv + xp * (1.f - mv));
    xkvr[2 * SZ + idx] = __float2bfloat16(xc * mr + xp * (1.f - mr));
}

// 64x64-tile GEMM: C[bi*64.., bj*64..] = A * B^T (row-major, K=768).
// K_STEP=64: 12 iters, 1-deep register prefetch, 8 MFMA/iter. [verbatim r10]
// epi: 0 = plain store, 1 = exp(min(v,60)), 2 = store only rows < 767
__device__ __forceinline__ void gemm_nt64(const __hip_bfloat16* __restrict__ A,
                                          const __hip_bfloat16* __restrict__ B,
                                          float* __restrict__ C,
                                          int bi, int bj, int epi)
{
    __shared__ __hip_bfloat16 lA[64][72];  // +8 pad: 2-way banks only (free)
    __shared__ __hip_bfloat16 lB[64][72];
    const int tid  = threadIdx.x;
    const int lane = tid & 63;
    const int wid  = tid >> 6;
    const int wr = wid >> 1, wc = wid & 1;  // 2x2 waves, 32x32 each
    const int srow = tid >> 2;              // staging row 0..63
    const int scol = (tid & 3) * 16;        // staging k-offset 0/16/32/48
    const int frow = lane & 15;             // MFMA A/B: row/col = lane&15
    const int kseg = (lane >> 4) * 8;       //           k = (lane>>4)*8 + j

    f32x4 acc[2][2] = {};

    const __hip_bfloat16* gA = A + (size_t)(bi * 64 + srow) * C_DIM + scol;
    const __hip_bfloat16* gB = B + (size_t)(bj * 64 + srow) * C_DIM + scol;

    s16x8 a0l = *(const s16x8*)gA,       a0h = *(const s16x8*)(gA + 8);
    s16x8 b0l = *(const s16x8*)gB,       b0h = *(const s16x8*)(gB + 8);
    for (int t = 0; t < 12; ++t) {
        s16x8 a1l, a1h, b1l, b1h;
        if (t < 11) {                       // prefetch next K-step: its L2
            const __hip_bfloat16* pA = gA + (t + 1) * 64;   // latency hides
            const __hip_bfloat16* pB = gB + (t + 1) * 64;   // under this
            a1l = *(const s16x8*)pA;  a1h = *(const s16x8*)(pA + 8);  // step's
            b1l = *(const s16x8*)pB;  b1h = *(const s16x8*)(pB + 8);  // MFMAs
        }
        __syncthreads();
        *(s16x8*)&lA[srow][scol]     = a0l;
        *(s16x8*)&lA[srow][scol + 8] = a0h;
        *(s16x8*)&lB[srow][scol]     = b0l;
        *(s16x8*)&lB[srow][scol + 8] = b0h;
        __syncthreads();
        s16x8 af[2][2], bfr[2][2];          // [ksub][m/n]
        #pragma unroll
        for (int ks = 0; ks < 2; ++ks) {
            #pragma unroll
            for (int m = 0; m < 2; ++m) {
                af[ks][m]  = *(const s16x8*)&lA[wr * 32 + m * 16 + frow][ks * 32 + kseg];
                bfr[ks][m] = *(const s16x8*)&lB[wc * 32 + m * 16 + frow][ks * 32 + kseg];
            }
        }
        #pragma unroll
        for (int ks = 0; ks < 2; ++ks)
            #pragma unroll
            for (int m = 0; m < 2; ++m)
                #pragma unroll
                for (int n = 0; n < 2; ++n)
                    acc[m][n] = __builtin_amdgcn_mfma_f32_16x16x32_bf16(
                        af[ks][m], bfr[ks][n], acc[m][n], 0, 0, 0);
        a0l = a1l; a0h = a1h; b0l = b1l; b0h = b1h;
    }

    // C/D layout: col = lane&15, row = (lane>>4)*4 + j   [m89-verified]
    int rbase = bi * 64 + wr * 32 + (lane >> 4) * 4;
    int cbase = bj * 64 + wc * 32 + (lane & 15);
    #pragma unroll
    for (int m = 0; m < 2; ++m) {
        #pragma unroll
        for (int n = 0; n < 2; ++n) {
            #pragma unroll
            for (int j = 0; j < 4; ++j) {
                int row = rbase + m * 16 + j;
                int col = cbase + n * 16;
                float v = acc[m][n][j];
                if (epi == 1) v = __expf(fminf(v, 60.f));
                if (epi != 2 || row < T_LEN)
                    C[(size_t)row * C_DIM + col] = v;
            }
        }
    }
}

__global__ __launch_bounds__(256) void gemm3_kernel(
    const __hip_bfloat16* __restrict__ xkvr,
    const __hip_bfloat16* __restrict__ Wb, float* __restrict__ kvr)
{
    int z = blockIdx.z;  // 0=k (exp epilogue), 1=v, 2=r
    gemm_nt64(xkvr + (size_t)z * SZ, Wb + (size_t)z * SZ, kvr + (size_t)z * SZ,
              blockIdx.x, blockIdx.y, z == 0 ? 1 : 0);
}

__global__ __launch_bounds__(256) void gemm_out_kernel(
    const __hip_bfloat16* __restrict__ rwkv,
    const __hip_bfloat16* __restrict__ Wo_b, float* __restrict__ out)
{
    gemm_nt64(rwkv, Wo_b, out, blockIdx.x, blockIdx.y, 2);
}

// Windowed decay scan [r2 structure; WARMUP 64->32]. Weight at lag Delta is
// exp(-Delta*e^td); at Delta=33 with td>=0.6 that's ~2e-26 — dropping lags
// >32 is ~1e-23 absolute, vastly below bf16 rounding. grid (3,192), 256 thr.
__global__ __launch_bounds__(256) void scan_kernel(
    const float* __restrict__ kb, const float* __restrict__ vb,
    const float* __restrict__ rb, const float* __restrict__ td,
    const float* __restrict__ tf, __hip_bfloat16* __restrict__ rwkv)
{
    int d  = blockIdx.x * 256 + threadIdx.x;  // grid.x = 3
    int t0 = blockIdx.y * R_CHUNK;
    float dm  = __expf(-__expf(td[d]));
    float etf = __expf(tf[d]);
    float a = 0.f, b = 0.f;
    // fixed-length warmup: t = t0-WARMUP .. t0-1 (clamped loads, zeroed wts)
    #pragma unroll 16
    for (int i = WARMUP; i >= 1; --i) {
        int t  = t0 - i;
        int tt = t < 0 ? 0 : t;
        float kk = kb[tt * C_DIM + d];
        float vv = vb[tt * C_DIM + d];
        if (t < 0) { kk = 0.f; vv = 0.f; }
        a = fmaf(dm, a, kk * vv);
        b = fmaf(dm, b, kk);
    }
    int t1 = min(t0 + R_CHUNK, T_LEN);
    #pragma unroll
    for (int t = t0; t < t1; ++t) {
        float kk = kb[t * C_DIM + d];
        float vv = vb[t * C_DIM + d];
        float kv = kk * vv;
        float wkv = fmaf(etf, kv, a);
        float wk  = fmaf(etf, kk, b) + 1e-8f;
        float rr  = rb[t * C_DIM + d];
        float sig = 1.f / (1.f + __expf(-rr));
        rwkv[t * C_DIM + d] = __float2bfloat16(sig * wkv / wk);
        a = fmaf(dm, a, kv);
        b = fmaf(dm, b, kk);
    }
}

extern "C" void kernel_launch(void* const* d_in, const int* in_sizes, int n_in,
                              void* d_out, int out_size, void* d_ws, size_t ws_size,
                              hipStream_t stream)
{
    const float* x   = (const float*)d_in[0];
    const float* td  = (const float*)d_in[1];
    const float* tf  = (const float*)d_in[2];
    const float* tmk = (const float*)d_in[3];
    const float* tmv = (const float*)d_in[4];
    const float* tmr = (const float*)d_in[5];
    const float* Wk  = (const float*)d_in[6];
    const float* Wv  = (const float*)d_in[7];
    const float* Wr  = (const float*)d_in[8];
    const float* Wo  = (const float*)d_in[9];
    float* out = (float*)d_out;

    char* ws = (char*)d_ws;
    __hip_bfloat16* xkvr = (__hip_bfloat16*)ws;
    __hip_bfloat16* Wb   = (__hip_bfloat16*)(ws + (size_t)3 * SZ * 2);
    float*          kvr  = (float*)(ws + (size_t)7 * SZ * 2);
    __hip_bfloat16* rwkv = (__hip_bfloat16*)(ws + (size_t)7 * SZ * 2 + (size_t)3 * SZ * 4);

    prep_kernel<<<dim3(SZ / 256, 5), 256, 0, stream>>>(
        x, tmk, tmv, tmr, Wk, Wv, Wr, Wo, xkvr, Wb, rwkv);
    gemm3_kernel<<<dim3(12, 12, 3), 256, 0, stream>>>(xkvr, Wb, kvr);
    scan_kernel<<<dim3(3, (T_LEN + R_CHUNK - 1) / R_CHUNK), 256, 0, stream>>>(
        kvr, kvr + SZ, kvr + 2 * SZ, td, tf, rwkv);
    gemm_out_kernel<<<dim3(12, 12), 256, 0, stream>>>(rwkv, Wb + (size_t)3 * SZ, out);
}

// Round 12
// 35.051 us; speedup vs baseline: 8.2053x; 1.0496x over previous
//
#include <hip/hip_runtime.h>
#include <hip/hip_bf16.h>

// RWKV TimeMix forward, MI355X — r11 anchor (36.8us) with ONE change:
// prep vectorized 4 elems/thread (float4 loads, short4 stores), grid (576,5).
// Ledger: r2=44.5; r9 +prefetch=41.2; r10 +K_STEP64=38.9; r11 +warmup32=36.8
// (all single-variable, all confirmed). r3/r6/r8 multi-change regressions;
// r5/r7 sw grid barriers ~100us/barrier — never again.
// ws layout (SZ = 768*768):
//   [0)          xkvr  bf16 3*SZ  (xk,xv,xr; row 767 zeroed)
//   [3*SZ*2)     Wb    bf16 4*SZ  (Wk,Wv,Wr,Wo)
//   [7*SZ*2)     kvr   f32  3*SZ  (k=exp(min(.,60)), v, r)  [T-major]
//   [7*SZ*2+3*SZ*4) rwkv bf16 SZ  (row 767 zeroed)

#define T_LEN 767
#define C_DIM 768
#define SZ (768 * 768)
#define R_CHUNK 4    // outputs per scan thread
#define WARMUP 32    // decay window; exp(-33*e^td)*|kv| ~ 1e-23 << tol

typedef __attribute__((ext_vector_type(4))) float f32x4;
typedef __attribute__((ext_vector_type(8))) short s16x8;
typedef __attribute__((ext_vector_type(4))) short s16x4;

__device__ __forceinline__ short bfbits(float f) {
    __hip_bfloat16 h = __float2bfloat16(f);
    return *reinterpret_cast<short*>(&h);
}

// Fused prep: grid (576, 5), 4 elems/thread. y==0: time-mix + bf16 cast.
// y in 1..4: Wk/Wv/Wr/Wo f32->bf16. Same arithmetic as r11's scalar version.
__global__ __launch_bounds__(256) void prep_kernel(
    const float* __restrict__ x, const float* __restrict__ tmk,
    const float* __restrict__ tmv, const float* __restrict__ tmr,
    const float* __restrict__ Wk, const float* __restrict__ Wv,
    const float* __restrict__ Wr, const float* __restrict__ Wo,
    __hip_bfloat16* __restrict__ xkvr, __hip_bfloat16* __restrict__ Wb,
    __hip_bfloat16* __restrict__ rwkv)
{
    int base = (blockIdx.x * 256 + threadIdx.x) * 4;   // 0..SZ-4, 4-aligned
    int job = blockIdx.y;
    if (job != 0) {
        const float* src = (job == 1) ? Wk : (job == 2) ? Wv : (job == 3) ? Wr : Wo;
        f32x4 w = *(const f32x4*)(src + base);
        s16x4 o;
        #pragma unroll
        for (int j = 0; j < 4; ++j) o[j] = bfbits(w[j]);
        *(s16x4*)(Wb + (size_t)(job - 1) * SZ + base) = o;
        return;
    }
    int t = base / C_DIM;          // 768 % 4 == 0: group never crosses rows
    int c = base - t * C_DIM;
    if (t == T_LEN) {
        s16x4 z = {0, 0, 0, 0};
        *(s16x4*)(xkvr + base) = z;
        *(s16x4*)(xkvr + SZ + base) = z;
        *(s16x4*)(xkvr + 2 * SZ + base) = z;
        *(s16x4*)(rwkv + base) = z;   // padded row for final GEMM
        return;
    }
    f32x4 xc = *(const f32x4*)(x + base);
    f32x4 xp = {0, 0, 0, 0};
    if (t) xp = *(const f32x4*)(x + base - C_DIM);
    f32x4 mk = *(const f32x4*)(tmk + c);
    f32x4 mv = *(const f32x4*)(tmv + c);
    f32x4 mr = *(const f32x4*)(tmr + c);
    s16x4 ok, ov, orr;
    #pragma unroll
    for (int j = 0; j < 4; ++j) {
        ok[j]  = bfbits(xc[j] * mk[j] + xp[j] * (1.f - mk[j]));
        ov[j]  = bfbits(xc[j] * mv[j] + xp[j] * (1.f - mv[j]));
        orr[j] = bfbits(xc[j] * mr[j] + xp[j] * (1.f - mr[j]));
    }
    *(s16x4*)(xkvr + base) = ok;
    *(s16x4*)(xkvr + SZ + base) = ov;
    *(s16x4*)(xkvr + 2 * SZ + base) = orr;
}

// 64x64-tile GEMM: C[bi*64.., bj*64..] = A * B^T (row-major, K=768).
// K_STEP=64: 12 iters, 1-deep register prefetch, 8 MFMA/iter. [verbatim r10]
// epi: 0 = plain store, 1 = exp(min(v,60)), 2 = store only rows < 767
__device__ __forceinline__ void gemm_nt64(const __hip_bfloat16* __restrict__ A,
                                          const __hip_bfloat16* __restrict__ B,
                                          float* __restrict__ C,
                                          int bi, int bj, int epi)
{
    __shared__ __hip_bfloat16 lA[64][72];  // +8 pad: 2-way banks only (free)
    __shared__ __hip_bfloat16 lB[64][72];
    const int tid  = threadIdx.x;
    const int lane = tid & 63;
    const int wid  = tid >> 6;
    const int wr = wid >> 1, wc = wid & 1;  // 2x2 waves, 32x32 each
    const int srow = tid >> 2;              // staging row 0..63
    const int scol = (tid & 3) * 16;        // staging k-offset 0/16/32/48
    const int frow = lane & 15;             // MFMA A/B: row/col = lane&15
    const int kseg = (lane >> 4) * 8;       //           k = (lane>>4)*8 + j

    f32x4 acc[2][2] = {};

    const __hip_bfloat16* gA = A + (size_t)(bi * 64 + srow) * C_DIM + scol;
    const __hip_bfloat16* gB = B + (size_t)(bj * 64 + srow) * C_DIM + scol;

    s16x8 a0l = *(const s16x8*)gA,       a0h = *(const s16x8*)(gA + 8);
    s16x8 b0l = *(const s16x8*)gB,       b0h = *(const s16x8*)(gB + 8);
    for (int t = 0; t < 12; ++t) {
        s16x8 a1l, a1h, b1l, b1h;
        if (t < 11) {                       // prefetch next K-step: its L2
            const __hip_bfloat16* pA = gA + (t + 1) * 64;   // latency hides
            const __hip_bfloat16* pB = gB + (t + 1) * 64;   // under this
            a1l = *(const s16x8*)pA;  a1h = *(const s16x8*)(pA + 8);  // step's
            b1l = *(const s16x8*)pB;  b1h = *(const s16x8*)(pB + 8);  // MFMAs
        }
        __syncthreads();
        *(s16x8*)&lA[srow][scol]     = a0l;
        *(s16x8*)&lA[srow][scol + 8] = a0h;
        *(s16x8*)&lB[srow][scol]     = b0l;
        *(s16x8*)&lB[srow][scol + 8] = b0h;
        __syncthreads();
        s16x8 af[2][2], bfr[2][2];          // [ksub][m/n]
        #pragma unroll
        for (int ks = 0; ks < 2; ++ks) {
            #pragma unroll
            for (int m = 0; m < 2; ++m) {
                af[ks][m]  = *(const s16x8*)&lA[wr * 32 + m * 16 + frow][ks * 32 + kseg];
                bfr[ks][m] = *(const s16x8*)&lB[wc * 32 + m * 16 + frow][ks * 32 + kseg];
            }
        }
        #pragma unroll
        for (int ks = 0; ks < 2; ++ks)
            #pragma unroll
            for (int m = 0; m < 2; ++m)
                #pragma unroll
                for (int n = 0; n < 2; ++n)
                    acc[m][n] = __builtin_amdgcn_mfma_f32_16x16x32_bf16(
                        af[ks][m], bfr[ks][n], acc[m][n], 0, 0, 0);
        a0l = a1l; a0h = a1h; b0l = b1l; b0h = b1h;
    }

    // C/D layout: col = lane&15, row = (lane>>4)*4 + j   [m89-verified]
    int rbase = bi * 64 + wr * 32 + (lane >> 4) * 4;
    int cbase = bj * 64 + wc * 32 + (lane & 15);
    #pragma unroll
    for (int m = 0; m < 2; ++m) {
        #pragma unroll
        for (int n = 0; n < 2; ++n) {
            #pragma unroll
            for (int j = 0; j < 4; ++j) {
                int row = rbase + m * 16 + j;
                int col = cbase + n * 16;
                float v = acc[m][n][j];
                if (epi == 1) v = __expf(fminf(v, 60.f));
                if (epi != 2 || row < T_LEN)
                    C[(size_t)row * C_DIM + col] = v;
            }
        }
    }
}

__global__ __launch_bounds__(256) void gemm3_kernel(
    const __hip_bfloat16* __restrict__ xkvr,
    const __hip_bfloat16* __restrict__ Wb, float* __restrict__ kvr)
{
    int z = blockIdx.z;  // 0=k (exp epilogue), 1=v, 2=r
    gemm_nt64(xkvr + (size_t)z * SZ, Wb + (size_t)z * SZ, kvr + (size_t)z * SZ,
              blockIdx.x, blockIdx.y, z == 0 ? 1 : 0);
}

__global__ __launch_bounds__(256) void gemm_out_kernel(
    const __hip_bfloat16* __restrict__ rwkv,
    const __hip_bfloat16* __restrict__ Wo_b, float* __restrict__ out)
{
    gemm_nt64(rwkv, Wo_b, out, blockIdx.x, blockIdx.y, 2);
}

// Windowed decay scan [verbatim r11]. grid (3,192), 256 thr.
__global__ __launch_bounds__(256) void scan_kernel(
    const float* __restrict__ kb, const float* __restrict__ vb,
    const float* __restrict__ rb, const float* __restrict__ td,
    const float* __restrict__ tf, __hip_bfloat16* __restrict__ rwkv)
{
    int d  = blockIdx.x * 256 + threadIdx.x;  // grid.x = 3
    int t0 = blockIdx.y * R_CHUNK;
    float dm  = __expf(-__expf(td[d]));
    float etf = __expf(tf[d]);
    float a = 0.f, b = 0.f;
    // fixed-length warmup: t = t0-WARMUP .. t0-1 (clamped loads, zeroed wts)
    #pragma unroll 16
    for (int i = WARMUP; i >= 1; --i) {
        int t  = t0 - i;
        int tt = t < 0 ? 0 : t;
        float kk = kb[tt * C_DIM + d];
        float vv = vb[tt * C_DIM + d];
        if (t < 0) { kk = 0.f; vv = 0.f; }
        a = fmaf(dm, a, kk * vv);
        b = fmaf(dm, b, kk);
    }
    int t1 = min(t0 + R_CHUNK, T_LEN);
    #pragma unroll
    for (int t = t0; t < t1; ++t) {
        float kk = kb[t * C_DIM + d];
        float vv = vb[t * C_DIM + d];
        float kv = kk * vv;
        float wkv = fmaf(etf, kv, a);
        float wk  = fmaf(etf, kk, b) + 1e-8f;
        float rr  = rb[t * C_DIM + d];
        float sig = 1.f / (1.f + __expf(-rr));
        rwkv[t * C_DIM + d] = __float2bfloat16(sig * wkv / wk);
        a = fmaf(dm, a, kv);
        b = fmaf(dm, b, kk);
    }
}

extern "C" void kernel_launch(void* const* d_in, const int* in_sizes, int n_in,
                              void* d_out, int out_size, void* d_ws, size_t ws_size,
                              hipStream_t stream)
{
    const float* x   = (const float*)d_in[0];
    const float* td  = (const float*)d_in[1];
    const float* tf  = (const float*)d_in[2];
    const float* tmk = (const float*)d_in[3];
    const float* tmv = (const float*)d_in[4];
    const float* tmr = (const float*)d_in[5];
    const float* Wk  = (const float*)d_in[6];
    const float* Wv  = (const float*)d_in[7];
    const float* Wr  = (const float*)d_in[8];
    const float* Wo  = (const float*)d_in[9];
    float* out = (float*)d_out;

    char* ws = (char*)d_ws;
    __hip_bfloat16* xkvr = (__hip_bfloat16*)ws;
    __hip_bfloat16* Wb   = (__hip_bfloat16*)(ws + (size_t)3 * SZ * 2);
    float*          kvr  = (float*)(ws + (size_t)7 * SZ * 2);
    __hip_bfloat16* rwkv = (__hip_bfloat16*)(ws + (size_t)7 * SZ * 2 + (size_t)3 * SZ * 4);

    prep_kernel<<<dim3(SZ / 1024, 5), 256, 0, stream>>>(
        x, tmk, tmv, tmr, Wk, Wv, Wr, Wo, xkvr, Wb, rwkv);
    gemm3_kernel<<<dim3(12, 12, 3), 256, 0, stream>>>(xkvr, Wb, kvr);
    scan_kernel<<<dim3(3, (T_LEN + R_CHUNK - 1) / R_CHUNK), 256, 0, stream>>>(
        kvr, kvr + SZ, kvr + 2 * SZ, td, tf, rwkv);
    gemm_out_kernel<<<dim3(12, 12), 256, 0, stream>>>(rwkv, Wb + (size_t)3 * SZ, out);
}

// Round 13
// 33.984 us; speedup vs baseline: 8.4629x; 1.0314x over previous
//
#include <hip/hip_runtime.h>
#include <hip/hip_bf16.h>

// RWKV TimeMix forward, MI355X — r12 anchor (35.0us) with ONE change:
// scan R_CHUNK 4 -> 8 (warmup amortized over 2x outputs: 9 -> 5 loads/output).
// Ledger: r2=44.5; r9 +prefetch=41.2; r10 +K_STEP64=38.9; r11 +warmup32=36.8;
// r12 +prep-vec=35.0 (all single-variable, confirmed). r6 attributed: W-cast
// in B-staging = +26us (K-step critical path is sacred). r5/r7: sw grid
// barriers ~100us/barrier (incl. AMD grid.sync) — mega-kernel dead.
// ws layout (SZ = 768*768):
//   [0)          xkvr  bf16 3*SZ  (xk,xv,xr; row 767 zeroed)
//   [3*SZ*2)     Wb    bf16 4*SZ  (Wk,Wv,Wr,Wo)
//   [7*SZ*2)     kvr   f32  3*SZ  (k=exp(min(.,60)), v, r)  [T-major]
//   [7*SZ*2+3*SZ*4) rwkv bf16 SZ  (row 767 zeroed)

#define T_LEN 767
#define C_DIM 768
#define SZ (768 * 768)
#define R_CHUNK 8    // outputs per scan thread
#define WARMUP 32    // decay window; exp(-33*e^td)*|kv| ~ 1e-23 << tol

typedef __attribute__((ext_vector_type(4))) float f32x4;
typedef __attribute__((ext_vector_type(8))) short s16x8;
typedef __attribute__((ext_vector_type(4))) short s16x4;

__device__ __forceinline__ short bfbits(float f) {
    __hip_bfloat16 h = __float2bfloat16(f);
    return *reinterpret_cast<short*>(&h);
}

// Fused prep: grid (576, 5), 4 elems/thread. y==0: time-mix + bf16 cast.
// y in 1..4: Wk/Wv/Wr/Wo f32->bf16.   [verbatim r12]
__global__ __launch_bounds__(256) void prep_kernel(
    const float* __restrict__ x, const float* __restrict__ tmk,
    const float* __restrict__ tmv, const float* __restrict__ tmr,
    const float* __restrict__ Wk, const float* __restrict__ Wv,
    const float* __restrict__ Wr, const float* __restrict__ Wo,
    __hip_bfloat16* __restrict__ xkvr, __hip_bfloat16* __restrict__ Wb,
    __hip_bfloat16* __restrict__ rwkv)
{
    int base = (blockIdx.x * 256 + threadIdx.x) * 4;   // 0..SZ-4, 4-aligned
    int job = blockIdx.y;
    if (job != 0) {
        const float* src = (job == 1) ? Wk : (job == 2) ? Wv : (job == 3) ? Wr : Wo;
        f32x4 w = *(const f32x4*)(src + base);
        s16x4 o;
        #pragma unroll
        for (int j = 0; j < 4; ++j) o[j] = bfbits(w[j]);
        *(s16x4*)(Wb + (size_t)(job - 1) * SZ + base) = o;
        return;
    }
    int t = base / C_DIM;          // 768 % 4 == 0: group never crosses rows
    int c = base - t * C_DIM;
    if (t == T_LEN) {
        s16x4 z = {0, 0, 0, 0};
        *(s16x4*)(xkvr + base) = z;
        *(s16x4*)(xkvr + SZ + base) = z;
        *(s16x4*)(xkvr + 2 * SZ + base) = z;
        *(s16x4*)(rwkv + base) = z;   // padded row for final GEMM
        return;
    }
    f32x4 xc = *(const f32x4*)(x + base);
    f32x4 xp = {0, 0, 0, 0};
    if (t) xp = *(const f32x4*)(x + base - C_DIM);
    f32x4 mk = *(const f32x4*)(tmk + c);
    f32x4 mv = *(const f32x4*)(tmv + c);
    f32x4 mr = *(const f32x4*)(tmr + c);
    s16x4 ok, ov, orr;
    #pragma unroll
    for (int j = 0; j < 4; ++j) {
        ok[j]  = bfbits(xc[j] * mk[j] + xp[j] * (1.f - mk[j]));
        ov[j]  = bfbits(xc[j] * mv[j] + xp[j] * (1.f - mv[j]));
        orr[j] = bfbits(xc[j] * mr[j] + xp[j] * (1.f - mr[j]));
    }
    *(s16x4*)(xkvr + base) = ok;
    *(s16x4*)(xkvr + SZ + base) = ov;
    *(s16x4*)(xkvr + 2 * SZ + base) = orr;
}

// 64x64-tile GEMM: C[bi*64.., bj*64..] = A * B^T (row-major, K=768).
// K_STEP=64: 12 iters, 1-deep register prefetch, 8 MFMA/iter. [verbatim r10]
// epi: 0 = plain store, 1 = exp(min(v,60)), 2 = store only rows < 767
__device__ __forceinline__ void gemm_nt64(const __hip_bfloat16* __restrict__ A,
                                          const __hip_bfloat16* __restrict__ B,
                                          float* __restrict__ C,
                                          int bi, int bj, int epi)
{
    __shared__ __hip_bfloat16 lA[64][72];  // +8 pad: 2-way banks only (free)
    __shared__ __hip_bfloat16 lB[64][72];
    const int tid  = threadIdx.x;
    const int lane = tid & 63;
    const int wid  = tid >> 6;
    const int wr = wid >> 1, wc = wid & 1;  // 2x2 waves, 32x32 each
    const int srow = tid >> 2;              // staging row 0..63
    const int scol = (tid & 3) * 16;        // staging k-offset 0/16/32/48
    const int frow = lane & 15;             // MFMA A/B: row/col = lane&15
    const int kseg = (lane >> 4) * 8;       //           k = (lane>>4)*8 + j

    f32x4 acc[2][2] = {};

    const __hip_bfloat16* gA = A + (size_t)(bi * 64 + srow) * C_DIM + scol;
    const __hip_bfloat16* gB = B + (size_t)(bj * 64 + srow) * C_DIM + scol;

    s16x8 a0l = *(const s16x8*)gA,       a0h = *(const s16x8*)(gA + 8);
    s16x8 b0l = *(const s16x8*)gB,       b0h = *(const s16x8*)(gB + 8);
    for (int t = 0; t < 12; ++t) {
        s16x8 a1l, a1h, b1l, b1h;
        if (t < 11) {                       // prefetch next K-step: its L2
            const __hip_bfloat16* pA = gA + (t + 1) * 64;   // latency hides
            const __hip_bfloat16* pB = gB + (t + 1) * 64;   // under this
            a1l = *(const s16x8*)pA;  a1h = *(const s16x8*)(pA + 8);  // step's
            b1l = *(const s16x8*)pB;  b1h = *(const s16x8*)(pB + 8);  // MFMAs
        }
        __syncthreads();
        *(s16x8*)&lA[srow][scol]     = a0l;
        *(s16x8*)&lA[srow][scol + 8] = a0h;
        *(s16x8*)&lB[srow][scol]     = b0l;
        *(s16x8*)&lB[srow][scol + 8] = b0h;
        __syncthreads();
        s16x8 af[2][2], bfr[2][2];          // [ksub][m/n]
        #pragma unroll
        for (int ks = 0; ks < 2; ++ks) {
            #pragma unroll
            for (int m = 0; m < 2; ++m) {
                af[ks][m]  = *(const s16x8*)&lA[wr * 32 + m * 16 + frow][ks * 32 + kseg];
                bfr[ks][m] = *(const s16x8*)&lB[wc * 32 + m * 16 + frow][ks * 32 + kseg];
            }
        }
        #pragma unroll
        for (int ks = 0; ks < 2; ++ks)
            #pragma unroll
            for (int m = 0; m < 2; ++m)
                #pragma unroll
                for (int n = 0; n < 2; ++n)
                    acc[m][n] = __builtin_amdgcn_mfma_f32_16x16x32_bf16(
                        af[ks][m], bfr[ks][n], acc[m][n], 0, 0, 0);
        a0l = a1l; a0h = a1h; b0l = b1l; b0h = b1h;
    }

    // C/D layout: col = lane&15, row = (lane>>4)*4 + j   [m89-verified]
    int rbase = bi * 64 + wr * 32 + (lane >> 4) * 4;
    int cbase = bj * 64 + wc * 32 + (lane & 15);
    #pragma unroll
    for (int m = 0; m < 2; ++m) {
        #pragma unroll
        for (int n = 0; n < 2; ++n) {
            #pragma unroll
            for (int j = 0; j < 4; ++j) {
                int row = rbase + m * 16 + j;
                int col = cbase + n * 16;
                float v = acc[m][n][j];
                if (epi == 1) v = __expf(fminf(v, 60.f));
                if (epi != 2 || row < T_LEN)
                    C[(size_t)row * C_DIM + col] = v;
            }
        }
    }
}

__global__ __launch_bounds__(256) void gemm3_kernel(
    const __hip_bfloat16* __restrict__ xkvr,
    const __hip_bfloat16* __restrict__ Wb, float* __restrict__ kvr)
{
    int z = blockIdx.z;  // 0=k (exp epilogue), 1=v, 2=r
    gemm_nt64(xkvr + (size_t)z * SZ, Wb + (size_t)z * SZ, kvr + (size_t)z * SZ,
              blockIdx.x, blockIdx.y, z == 0 ? 1 : 0);
}

__global__ __launch_bounds__(256) void gemm_out_kernel(
    const __hip_bfloat16* __restrict__ rwkv,
    const __hip_bfloat16* __restrict__ Wo_b, float* __restrict__ out)
{
    gemm_nt64(rwkv, Wo_b, out, blockIdx.x, blockIdx.y, 2);
}

// Windowed decay scan [r11 structure; R_CHUNK 4->8]. grid (3,96), 256 thr.
__global__ __launch_bounds__(256) void scan_kernel(
    const float* __restrict__ kb, const float* __restrict__ vb,
    const float* __restrict__ rb, const float* __restrict__ td,
    const float* __restrict__ tf, __hip_bfloat16* __restrict__ rwkv)
{
    int d  = blockIdx.x * 256 + threadIdx.x;  // grid.x = 3
    int t0 = blockIdx.y * R_CHUNK;
    float dm  = __expf(-__expf(td[d]));
    float etf = __expf(tf[d]);
    float a = 0.f, b = 0.f;
    // fixed-length warmup: t = t0-WARMUP .. t0-1 (clamped loads, zeroed wts)
    #pragma unroll 16
    for (int i = WARMUP; i >= 1; --i) {
        int t  = t0 - i;
        int tt = t < 0 ? 0 : t;
        float kk = kb[tt * C_DIM + d];
        float vv = vb[tt * C_DIM + d];
        if (t < 0) { kk = 0.f; vv = 0.f; }
        a = fmaf(dm, a, kk * vv);
        b = fmaf(dm, b, kk);
    }
    int t1 = min(t0 + R_CHUNK, T_LEN);
    #pragma unroll
    for (int t = t0; t < t1; ++t) {
        float kk = kb[t * C_DIM + d];
        float vv = vb[t * C_DIM + d];
        float kv = kk * vv;
        float wkv = fmaf(etf, kv, a);
        float wk  = fmaf(etf, kk, b) + 1e-8f;
        float rr  = rb[t * C_DIM + d];
        float sig = 1.f / (1.f + __expf(-rr));
        rwkv[t * C_DIM + d] = __float2bfloat16(sig * wkv / wk);
        a = fmaf(dm, a, kv);
        b = fmaf(dm, b, kk);
    }
}

extern "C" void kernel_launch(void* const* d_in, const int* in_sizes, int n_in,
                              void* d_out, int out_size, void* d_ws, size_t ws_size,
                              hipStream_t stream)
{
    const float* x   = (const float*)d_in[0];
    const float* td  = (const float*)d_in[1];
    const float* tf  = (const float*)d_in[2];
    const float* tmk = (const float*)d_in[3];
    const float* tmv = (const float*)d_in[4];
    const float* tmr = (const float*)d_in[5];
    const float* Wk  = (const float*)d_in[6];
    const float* Wv  = (const float*)d_in[7];
    const float* Wr  = (const float*)d_in[8];
    const float* Wo  = (const float*)d_in[9];
    float* out = (float*)d_out;

    char* ws = (char*)d_ws;
    __hip_bfloat16* xkvr = (__hip_bfloat16*)ws;
    __hip_bfloat16* Wb   = (__hip_bfloat16*)(ws + (size_t)3 * SZ * 2);
    float*          kvr  = (float*)(ws + (size_t)7 * SZ * 2);
    __hip_bfloat16* rwkv = (__hip_bfloat16*)(ws + (size_t)7 * SZ * 2 + (size_t)3 * SZ * 4);

    prep_kernel<<<dim3(SZ / 1024, 5), 256, 0, stream>>>(
        x, tmk, tmv, tmr, Wk, Wv, Wr, Wo, xkvr, Wb, rwkv);
    gemm3_kernel<<<dim3(12, 12, 3), 256, 0, stream>>>(xkvr, Wb, kvr);
    scan_kernel<<<dim3(3, (T_LEN + R_CHUNK - 1) / R_CHUNK), 256, 0, stream>>>(
        kvr, kvr + SZ, kvr + 2 * SZ, td, tf, rwkv);
    gemm_out_kernel<<<dim3(12, 12), 256, 0, stream>>>(rwkv, Wb + (size_t)3 * SZ, out);
}